// Round 1
// 6658.514 us; speedup vs baseline: 3.3624x; 3.3624x over previous
//
#include <hip/hip_runtime.h>
#include <hip/hip_bf16.h>
#include <math.h>

using bf16 = __hip_bfloat16;
typedef long long i64;
typedef _Float16 f16;
typedef _Float16 half8 __attribute__((ext_vector_type(8)));
typedef float f32x4 __attribute__((ext_vector_type(4)));
typedef unsigned short us8 __attribute__((ext_vector_type(8)));

// ---------------- helpers ----------------
__device__ __forceinline__ float bf2f(unsigned short u) {
    union { unsigned int i; float f; } v; v.i = ((unsigned int)u) << 16; return v.f;
}
// mode-aware external-input load (idx in elements): mode0 = bf16, mode1 = f32
__device__ __forceinline__ float ldm(const void* p, size_t i, int mode) {
    return mode ? ((const float*)p)[i] : bf2f(((const unsigned short*)p)[i]);
}
__device__ __forceinline__ void stm(void* p, size_t i, int f32, float v) {
    if (f32) ((float*)p)[i] = v;
    else ((unsigned short*)p)[i] = __bfloat16_as_ushort(__float2bfloat16(v));
}
__device__ __forceinline__ float gelu_exact(float x) {
    return 0.5f * x * (1.0f + erff(x * 0.70710678118654752f));
}
__device__ __forceinline__ half8 h8zero() {
    half8 h = {(f16)0,(f16)0,(f16)0,(f16)0,(f16)0,(f16)0,(f16)0,(f16)0};
    return h;
}
__device__ __forceinline__ half8 bf8_cvt(us8 u) {
    half8 h;
    #pragma unroll
    for (int j = 0; j < 8; j++) h[j] = (f16)bf2f(u[j]);
    return h;
}

// ---------------- dtype probe ----------------
__global__ __launch_bounds__(256) void detect_kernel(
    const void* __restrict__ x, int n, int* __restrict__ modep)
{
    __shared__ float red[256];
    float m = 0.0f;
    for (int i = threadIdx.x; i < n; i += 256) {
        float v = fabsf(bf2f(((const unsigned short*)x)[i]));
        if (!isfinite(v)) v = 1e30f;
        m = fmaxf(m, v);
    }
    red[threadIdx.x] = m;
    __syncthreads();
    for (int s = 128; s; s >>= 1) {
        if (threadIdx.x < s) red[threadIdx.x] = fmaxf(red[threadIdx.x], red[threadIdx.x + s]);
        __syncthreads();
    }
    if (threadIdx.x == 0) *modep = (red[0] > 1e4f) ? 1 : 0;
}

// ---------------- ex MLP ----------------
__global__ __launch_bounds__(256) void ex1_kernel(
    const void* __restrict__ ex, const void* __restrict__ w1,
    const void* __restrict__ b1, float* __restrict__ h1, const int* __restrict__ modep)
{
    const int mode = *modep;
    __shared__ float exs[64];
    const int tid = threadIdx.x;
    const int b = blockIdx.y;
    const int n = blockIdx.x * 256 + tid;
    if (tid < 64) exs[tid] = ldm(ex, b * 64 + tid, mode);
    __syncthreads();
    float acc = ldm(b1, n, mode);
    for (int k = 0; k < 64; k++) acc += exs[k] * ldm(w1, (size_t)k * 2048 + n, mode);
    h1[(size_t)b * 2048 + n] = acc;
}

__global__ __launch_bounds__(256) void ex2_kernel(
    const float* __restrict__ h1, const void* __restrict__ w2,
    const void* __restrict__ b2, float* __restrict__ ex_enc, const int* __restrict__ modep)
{
    const int mode = *modep;
    __shared__ float hs[2048];
    const int tid = threadIdx.x;
    const int b = blockIdx.y;
    const int n = blockIdx.x * 256 + tid;
    for (int idx = tid; idx < 2048; idx += 256) hs[idx] = h1[(size_t)b * 2048 + idx];
    __syncthreads();
    float acc = ldm(b2, n, mode);
    for (int k = 0; k < 2048; k++) acc += hs[k] * ldm(w2, (size_t)k * 512 + n, mode);
    ex_enc[(size_t)b * 512 + n] = tanhf(acc);
}

// ---------------- conv1 ----------------
__global__ __launch_bounds__(256) void conv1_kernel(
    const void* __restrict__ x, const void* __restrict__ w,
    const void* __restrict__ b, f16* __restrict__ out, const int* __restrict__ modep)
{
    const int mode = *modep;
    const int pix = blockIdx.x;
    const int bb = pix / 225, ij = pix % 225;
    const int i = ij / 15, j = ij % 15;
    const int tid = threadIdx.x;
    __shared__ float xs[18];
    if (tid < 18) {
        int c = tid & 1, dj = (tid >> 1) % 3, di = tid / 6;
        int ii = i + di - 1, jj = j + dj - 1;
        float v = 0.0f;
        if (ii >= 0 && ii < 15 && jj >= 0 && jj < 15)
            v = ldm(x, ((size_t)(bb * 15 + ii) * 15 + jj) * 2 + c, mode);
        xs[tid] = v;
    }
    __syncthreads();
    #pragma unroll
    for (int rep = 0; rep < 2; rep++) {
        int n = tid + rep * 256;
        float acc = ldm(b, n, mode);
        #pragma unroll
        for (int t = 0; t < 18; t++) acc += xs[t] * ldm(w, (size_t)t * 512 + n, mode);
        out[(size_t)pix * 512 + n] = (f16)gelu_exact(acc);
    }
}

// ---------------- weight transpose: W[k][n] (ext dtype) -> Wt[n][k] fp16 ----------------
// grid: (N/32, K/32), block 256
__global__ __launch_bounds__(256) void transpose_w(
    const void* __restrict__ W, int ldw, i64 eoff, int K,
    f16* __restrict__ Wt, const int* __restrict__ modep)
{
    const int mode = *modep;
    __shared__ f16 ts[32][33];
    const int k0 = blockIdx.y << 5, n0 = blockIdx.x << 5;
    const int r = threadIdx.x >> 3, c = (threadIdx.x & 7) << 2;
    const size_t base = (size_t)eoff + (size_t)(k0 + r) * ldw + n0 + c;
    #pragma unroll
    for (int q = 0; q < 4; q++) ts[r][c + q] = (f16)ldm(W, base + q, mode);
    __syncthreads();
    f16* dst = Wt + (size_t)(n0 + r) * K + k0 + c;
    #pragma unroll
    for (int q = 0; q < 4; q++) dst[q] = ts[c + q][r];
}

// ---------------- MFMA GEMM (fp16 in, fp32 acc, fp16 out) ----------------
// C[row][col] = act( A[a_eoff + row*lda + k] @ Wt[col][k] + bias[b_eoff+col] )
// A: internal fp16 unless a_ext (then ext f32/bf16 per mode). conv: A is conv1
// output [64][15][15][512] fp16 and K=4608 walks the 9 taps (implicit im2col).
// act: 0 none, 1 gelu, 2 conv2-epilogue (gelu*sqrt(512) + ex_enc + spe).
// BM=BN=128, BK=32, 4 waves (2x2), wave tile 64x64 (4x4 frags of 16x16x32).
__global__ __launch_bounds__(256) void gemm_mfma(
    const void* __restrict__ A, int lda, int a_ext, i64 a_eoff, int M,
    const f16* __restrict__ Wt,
    const void* __restrict__ bias, i64 b_eoff,
    f16* __restrict__ C, int ldc, i64 c_eoff,
    int K, int act, int conv, const float* __restrict__ ex_enc,
    const int* __restrict__ modep)
{
    const int mode = *modep;
    __shared__ __align__(16) f16 As[128][40];
    __shared__ __align__(16) f16 Bs[128][40];
    const int tid  = threadIdx.x;
    const int lane = tid & 63;
    const int wid  = tid >> 6;
    const int wm   = (wid >> 1) << 6;   // 0 or 64
    const int wn   = (wid & 1) << 6;    // 0 or 64
    const int bm   = blockIdx.y << 7;
    const int bn   = blockIdx.x << 7;

    // staging assignment: thread covers 16 contiguous k of one row
    const int srow = tid >> 1;          // 0..127
    const int scol = (tid & 1) << 4;    // 0 or 16
    const int garow = bm + srow;
    const bool arow_ok = garow < M;

    // conv (implicit im2col) per-thread pixel decomposition
    int cv_base = 0, cv_i = 0, cv_j = 0;
    if (conv) {
        int r = arow_ok ? garow : 0;
        int bb = r / 225, ij = r % 225;
        cv_i = ij / 15; cv_j = ij % 15;
        cv_base = bb * 225;
    }

    f32x4 acc[4][4] = {};

    half8 pa0, pa1, pb0, pb1;
    auto FETCH = [&](int k0) {
        const f16* bp = Wt + (size_t)(bn + srow) * (size_t)K + k0 + scol;
        pb0 = *(const half8*)bp;
        pb1 = *(const half8*)(bp + 8);
        pa0 = h8zero(); pa1 = h8zero();
        if (conv) {
            const int t = k0 >> 9;
            const int ii = cv_i + t / 3 - 1, jj = cv_j + t % 3 - 1;
            if (arow_ok && (unsigned)ii < 15u && (unsigned)jj < 15u) {
                const f16* ap = (const f16*)A
                    + ((size_t)(cv_base + ii * 15 + jj) << 9) + (k0 & 511) + scol;
                pa0 = *(const half8*)ap;
                pa1 = *(const half8*)(ap + 8);
            }
        } else if (arow_ok) {
            const size_t aidx = (size_t)a_eoff + (size_t)garow * lda + k0 + scol;
            if (!a_ext) {
                const f16* ap = (const f16*)A + aidx;
                pa0 = *(const half8*)ap;
                pa1 = *(const half8*)(ap + 8);
            } else if (mode) {
                const float* ap = (const float*)A + aidx;
                float4 f0 = *(const float4*)ap;
                float4 f1 = *(const float4*)(ap + 4);
                float4 f2 = *(const float4*)(ap + 8);
                float4 f3 = *(const float4*)(ap + 12);
                pa0[0]=(f16)f0.x; pa0[1]=(f16)f0.y; pa0[2]=(f16)f0.z; pa0[3]=(f16)f0.w;
                pa0[4]=(f16)f1.x; pa0[5]=(f16)f1.y; pa0[6]=(f16)f1.z; pa0[7]=(f16)f1.w;
                pa1[0]=(f16)f2.x; pa1[1]=(f16)f2.y; pa1[2]=(f16)f2.z; pa1[3]=(f16)f2.w;
                pa1[4]=(f16)f3.x; pa1[5]=(f16)f3.y; pa1[6]=(f16)f3.z; pa1[7]=(f16)f3.w;
            } else {
                const unsigned short* ap = (const unsigned short*)A + aidx;
                pa0 = bf8_cvt(*(const us8*)ap);
                pa1 = bf8_cvt(*(const us8*)(ap + 8));
            }
        }
    };

    FETCH(0);
    const int fra = wm + (lane & 15);
    const int frb = wn + (lane & 15);
    const int fk  = (lane >> 4) << 3;

    for (int k0 = 0; k0 < K; k0 += 32) {
        __syncthreads();   // previous tile's frag reads done
        *(half8*)&As[srow][scol]     = pa0;
        *(half8*)&As[srow][scol + 8] = pa1;
        *(half8*)&Bs[srow][scol]     = pb0;
        *(half8*)&Bs[srow][scol + 8] = pb1;
        __syncthreads();   // tile visible
        if (k0 + 32 < K) FETCH(k0 + 32);   // issue next-tile loads; latency hides under MFMA

        half8 af[4], bv[4];
        #pragma unroll
        for (int m = 0; m < 4; m++) af[m] = *(const half8*)&As[fra + m * 16][fk];
        #pragma unroll
        for (int n = 0; n < 4; n++) bv[n] = *(const half8*)&Bs[frb + n * 16][fk];
        #pragma unroll
        for (int m = 0; m < 4; m++)
            #pragma unroll
            for (int n = 0; n < 4; n++)
                acc[m][n] = __builtin_amdgcn_mfma_f32_16x16x32_f16(af[m], bv[n], acc[m][n], 0, 0, 0);
    }

    // ---------------- epilogue ----------------
    const int ccol0 = bn + wn + (lane & 15);
    float bvv[4];
    #pragma unroll
    for (int n = 0; n < 4; n++)
        bvv[n] = ldm(bias, (size_t)b_eoff + ccol0 + n * 16, mode);

    const float LG = 9.210340371976184f / 512.0f;
    const float SQ = 22.627416997969522f;
    float rate[4];
    if (act == 2) {
        #pragma unroll
        for (int n = 0; n < 4; n++) {
            int col = ccol0 + n * 16;
            rate[n] = expf(-(float)(2 * (col >> 1)) * LG);
        }
    }

    #pragma unroll
    for (int m = 0; m < 4; m++) {
        const int rowb = bm + wm + m * 16 + ((lane >> 4) << 2);
        #pragma unroll
        for (int r = 0; r < 4; r++) {
            const int row = rowb + r;
            if (row >= M) continue;
            float pr = 0.0f, pc = 0.0f; int bb = 0;
            if (act == 2) {
                bb = row / 225;
                int ij = row % 225;
                pr = (float)(ij / 15 - 7);
                pc = (float)(ij % 15 - 7);
            }
            #pragma unroll
            for (int n = 0; n < 4; n++) {
                const int col = ccol0 + n * 16;
                float v = acc[m][n][r] + bvv[n];
                if (act == 1) v = gelu_exact(v);
                else if (act == 2) {
                    float spe = ((col & 1) == 0) ? sinf(pr * rate[n]) : cosf(pc * rate[n]);
                    v = gelu_exact(v) * SQ + ex_enc[(size_t)bb * 512 + col] + spe;
                }
                C[(size_t)c_eoff + (size_t)row * ldc + col] = (f16)v;
            }
        }
    }
}

// ---------------- layernorm with residual ----------------
__global__ __launch_bounds__(256) void ln_res_kernel(
    const f16* __restrict__ x, const f16* __restrict__ res,
    const void* __restrict__ g, const void* __restrict__ b, i64 gb_eoff,
    void* __restrict__ dst, int dst_ext, const int* __restrict__ modep)
{
    const int mode = *modep;
    const size_t base = (size_t)blockIdx.x * 512;
    const int tid = threadIdx.x;
    float v0 = (float)x[base + tid] + (float)res[base + tid];
    float v1 = (float)x[base + 256 + tid] + (float)res[base + 256 + tid];
    __shared__ float ws[4], ws2[4];
    float s = v0 + v1;
    #pragma unroll
    for (int off = 32; off; off >>= 1) s += __shfl_xor(s, off);
    int wid = tid >> 6, lane = tid & 63;
    if (lane == 0) ws[wid] = s;
    __syncthreads();
    float mean = (ws[0] + ws[1] + ws[2] + ws[3]) * (1.0f / 512.0f);
    float d0 = v0 - mean, d1 = v1 - mean;
    float q = d0 * d0 + d1 * d1;
    #pragma unroll
    for (int off = 32; off; off >>= 1) q += __shfl_xor(q, off);
    if (lane == 0) ws2[wid] = q;
    __syncthreads();
    float var = (ws2[0] + ws2[1] + ws2[2] + ws2[3]) * (1.0f / 512.0f);
    float rs = rsqrtf(var + 1e-6f);
    const size_t go = (size_t)gb_eoff;
    float o0 = d0 * rs * ldm(g, go + tid, mode)       + ldm(b, go + tid, mode);
    float o1 = d1 * rs * ldm(g, go + 256 + tid, mode) + ldm(b, go + 256 + tid, mode);
    if (dst_ext) {
        stm(dst, base + tid,       mode, o0);
        stm(dst, base + 256 + tid, mode, o1);
    } else {
        ((f16*)dst)[base + tid]       = (f16)o0;
        ((f16*)dst)[base + 256 + tid] = (f16)o1;
    }
}

// ---------------- cross attention ----------------
__global__ __launch_bounds__(256) void cross_attn_kernel(
    const f16* __restrict__ q2, const f16* __restrict__ kv,
    const void* __restrict__ mask, f16* __restrict__ ao,
    int tok_base, int ntok, const int* __restrict__ modep)
{
    const int mode = *modep;
    const int gwid = (blockIdx.x * 256 + threadIdx.x) >> 6;
    const int lane = threadIdx.x & 63;
    if (gwid >= ntok * 8) return;
    const int t_local = gwid >> 3, head = gwid & 7;
    const int t = tok_base + t_local;
    float q = (float)q2[(size_t)t * 512 + head * 64 + lane];
    const size_t kvbase = (size_t)t_local * 12 * 1024 + head * 64 + lane;
    float l[12], vv[12];
    #pragma unroll
    for (int s = 0; s < 12; s++) {
        float kd = (float)kv[kvbase + (size_t)s * 1024];
        vv[s] = (float)kv[kvbase + (size_t)s * 1024 + 512];
        float p = q * kd;
        #pragma unroll
        for (int off = 32; off; off >>= 1) p += __shfl_xor(p, off);
        l[s] = p * 0.125f + ldm(mask, s, mode) * (-1e9f);
    }
    float mx = l[0];
    #pragma unroll
    for (int s = 1; s < 12; s++) mx = fmaxf(mx, l[s]);
    float sum = 0.0f;
    #pragma unroll
    for (int s = 0; s < 12; s++) { l[s] = expf(l[s] - mx); sum += l[s]; }
    float o = 0.0f;
    #pragma unroll
    for (int s = 0; s < 12; s++) o += l[s] * vv[s];
    o /= sum;
    ao[(size_t)t * 512 + head * 64 + lane] = (f16)o;
}

// ---------------- launch ----------------
extern "C" void kernel_launch(void* const* d_in, const int* in_sizes, int n_in,
                              void* d_out, int out_size, void* d_ws, size_t ws_size,
                              hipStream_t stream)
{
    const void* x        = d_in[0];
    const void* ex       = d_in[1];
    const void* enc      = d_in[2];
    const void* pad_mask = d_in[4];
    const void* ex_w1    = d_in[5];
    const void* ex_b1    = d_in[6];
    const void* ex_w2    = d_in[7];
    const void* ex_b2    = d_in[8];
    const void* conv_w1  = d_in[9];
    const void* conv_b1  = d_in[10];
    const void* conv_w2  = d_in[11];
    const void* conv_b2  = d_in[12];
    const void* wx_w     = d_in[13];
    const void* wx_b     = d_in[14];
    const void* wo1_w    = d_in[15];
    const void* wo1_b    = d_in[16];
    const void* wq_w     = d_in[17];
    const void* wq_b     = d_in[18];
    const void* wkv_w    = d_in[19];
    const void* wkv_b    = d_in[20];
    const void* wo2_w    = d_in[21];
    const void* wo2_b    = d_in[22];
    const void* ffn_w1   = d_in[23];
    const void* ffn_b1   = d_in[24];
    const void* ffn_w2   = d_in[25];
    const void* ffn_b2   = d_in[26];
    const void* ln_g     = d_in[27];
    const void* ln_b     = d_in[28];
    (void)ws_size; (void)in_sizes; (void)n_in; (void)out_size;

    char* wsb = (char*)d_ws;
    size_t off = 0;
    auto alloc = [&](size_t bytes) -> void* {
        void* p = wsb + off; off += (bytes + 255) & ~(size_t)255; return p;
    };
    int*   modep  = (int*)  alloc(256);
    float* ex_h1  = (float*)alloc((size_t)64 * 2048 * 4);
    float* ex_enc = (float*)alloc((size_t)64 * 512 * 4);
    f16*   buf_h  = (f16*)  alloc((size_t)14400 * 512 * 2);
    f16*   buf_a  = (f16*)  alloc((size_t)14400 * 512 * 2);
    f16*   buf_b  = (f16*)  alloc((size_t)14400 * 512 * 2);
    f16*   buf_t  = (f16*)  alloc((size_t)4800 * 2048 * 2);  // conv1 / kv-chunk / ffn-chunk
    // transposed-weight region (per-layer, reused; conv2t aliases it since it
    // is fully consumed before layer 0's transposes)
    f16*   wt_lay = (f16*)  alloc((size_t)3670016 * 2);       // 7.34 MB
    f16*   wt_v   = wt_lay;
    f16*   wt_o1  = wt_v  + 262144;
    f16*   wt_q   = wt_o1 + 262144;
    f16*   wt_kv  = wt_q  + 262144;
    f16*   wt_o2  = wt_kv + 524288;
    f16*   wt_f1  = wt_o2 + 262144;
    f16*   wt_f2  = wt_f1 + 1048576;
    f16*   wt_c2  = wt_lay;   // 2359296 elems <= 3670016

    detect_kernel<<<1, 256, 0, stream>>>(x, 28800, modep);
    ex1_kernel<<<dim3(8, 64), 256, 0, stream>>>(ex, ex_w1, ex_b1, ex_h1, modep);
    ex2_kernel<<<dim3(2, 64), 256, 0, stream>>>(ex_h1, ex_w2, ex_b2, ex_enc, modep);
    conv1_kernel<<<14400, 256, 0, stream>>>(x, conv_w1, conv_b1, buf_t, modep);

    // conv2 as implicit-im2col MFMA GEMM (M=14400, K=4608, N=512)
    transpose_w<<<dim3(16, 144), 256, 0, stream>>>(conv_w2, 512, 0, 4608, wt_c2, modep);
    gemm_mfma<<<dim3(4, 113), 256, 0, stream>>>(
        buf_t, 512, 0, 0, 14400, wt_c2, conv_b2, 0,
        buf_h, 512, 0, 4608, 2, 1, ex_enc, modep);

    for (int L = 0; L < 4; L++) {
        // per-layer weight transposes into fp16 [N][K]
        transpose_w<<<dim3(16, 16), 256, 0, stream>>>(wx_w, 1536, (i64)L * 512 * 1536 + 1024, 512, wt_v, modep);
        transpose_w<<<dim3(16, 16), 256, 0, stream>>>(wo1_w, 512, (i64)L * 512 * 512, 512, wt_o1, modep);
        transpose_w<<<dim3(16, 16), 256, 0, stream>>>(wq_w, 512, (i64)L * 512 * 512, 512, wt_q, modep);
        transpose_w<<<dim3(32, 16), 256, 0, stream>>>(wkv_w, 1024, (i64)L * 512 * 1024, 512, wt_kv, modep);
        transpose_w<<<dim3(16, 16), 256, 0, stream>>>(wo2_w, 512, (i64)L * 512 * 512, 512, wt_o2, modep);
        transpose_w<<<dim3(64, 16), 256, 0, stream>>>(ffn_w1, 2048, (i64)L * 512 * 2048, 512, wt_f1, modep);
        transpose_w<<<dim3(16, 64), 256, 0, stream>>>(ffn_w2, 512, (i64)L * 2048 * 512, 2048, wt_f2, modep);

        // v = h @ wx[:,1024:1536] + b  (self-attn over T=1 => attn = v)
        gemm_mfma<<<dim3(4, 113), 256, 0, stream>>>(
            buf_h, 512, 0, 0, 14400, wt_v, wx_b, (i64)L * 1536 + 1024,
            buf_a, 512, 0, 512, 0, 0, nullptr, modep);
        // attn1 = v @ wo1 + b
        gemm_mfma<<<dim3(4, 113), 256, 0, stream>>>(
            buf_a, 512, 0, 0, 14400, wt_o1, wo1_b, (i64)L * 512,
            buf_b, 512, 0, 512, 0, 0, nullptr, modep);
        ln_res_kernel<<<14400, 256, 0, stream>>>(
            buf_b, buf_h, ln_g, ln_b, (i64)(L * 3 + 0) * 512, buf_h, 0, modep);
        // q2 = out1 @ wq + b
        gemm_mfma<<<dim3(4, 113), 256, 0, stream>>>(
            buf_h, 512, 0, 0, 14400, wt_q, wq_b, (i64)L * 512,
            buf_a, 512, 0, 512, 0, 0, nullptr, modep);
        // cross attention: 20 chunks of 720 tokens (8640 enc rows each)
        for (int c = 0; c < 20; c++) {
            gemm_mfma<<<dim3(8, 68), 256, 0, stream>>>(
                enc, 512, 1, (i64)c * 8640 * 512, 8640, wt_kv, wkv_b, (i64)L * 1024,
                buf_t, 1024, 0, 512, 0, 0, nullptr, modep);
            cross_attn_kernel<<<1440, 256, 0, stream>>>(
                buf_a, buf_t, pad_mask, buf_b, c * 720, 720, modep);
        }
        // attn2 = ao @ wo2 + b
        gemm_mfma<<<dim3(4, 113), 256, 0, stream>>>(
            buf_b, 512, 0, 0, 14400, wt_o2, wo2_b, (i64)L * 512,
            buf_a, 512, 0, 512, 0, 0, nullptr, modep);
        ln_res_kernel<<<14400, 256, 0, stream>>>(
            buf_a, buf_h, ln_g, ln_b, (i64)(L * 3 + 1) * 512, buf_h, 0, modep);
        // FFN: 3 chunks of 4800 rows
        for (int c = 0; c < 3; c++) {
            gemm_mfma<<<dim3(16, 38), 256, 0, stream>>>(
                buf_h, 512, 0, (i64)c * 4800 * 512, 4800, wt_f1, ffn_b1, (i64)L * 2048,
                buf_t, 2048, 0, 512, 1, 0, nullptr, modep);
            gemm_mfma<<<dim3(4, 38), 256, 0, stream>>>(
                buf_t, 2048, 0, 0, 4800, wt_f2, ffn_b2, (i64)L * 512,
                buf_a, 512, (i64)c * 4800 * 512, 2048, 0, 0, nullptr, modep);
        }
        void* dst = (L == 3) ? d_out : (void*)buf_h;
        ln_res_kernel<<<14400, 256, 0, stream>>>(
            buf_a, buf_h, ln_g, ln_b, (i64)(L * 3 + 2) * 512, dst, (L == 3) ? 1 : 0, modep);
    }
}

// Round 2
// 3868.686 us; speedup vs baseline: 5.7871x; 1.7211x over previous
//
#include <hip/hip_runtime.h>
#include <hip/hip_bf16.h>
#include <math.h>

using bf16 = __hip_bfloat16;
typedef long long i64;
typedef _Float16 f16;
typedef _Float16 half4 __attribute__((ext_vector_type(4)));
typedef _Float16 half8 __attribute__((ext_vector_type(8)));
typedef float f32x4 __attribute__((ext_vector_type(4)));
typedef unsigned short us8 __attribute__((ext_vector_type(8)));

// ---------------- helpers ----------------
__device__ __forceinline__ float bf2f(unsigned short u) {
    union { unsigned int i; float f; } v; v.i = ((unsigned int)u) << 16; return v.f;
}
// mode-aware external-input load (idx in elements): mode0 = bf16, mode1 = f32
__device__ __forceinline__ float ldm(const void* p, size_t i, int mode) {
    return mode ? ((const float*)p)[i] : bf2f(((const unsigned short*)p)[i]);
}
__device__ __forceinline__ void stm(void* p, size_t i, int f32, float v) {
    if (f32) ((float*)p)[i] = v;
    else ((unsigned short*)p)[i] = __bfloat16_as_ushort(__float2bfloat16(v));
}
__device__ __forceinline__ float gelu_exact(float x) {
    return 0.5f * x * (1.0f + erff(x * 0.70710678118654752f));
}
__device__ __forceinline__ half8 h8zero() {
    half8 h = {(f16)0,(f16)0,(f16)0,(f16)0,(f16)0,(f16)0,(f16)0,(f16)0};
    return h;
}
__device__ __forceinline__ half8 bf8_cvt(us8 u) {
    half8 h;
    #pragma unroll
    for (int j = 0; j < 8; j++) h[j] = (f16)bf2f(u[j]);
    return h;
}

// ---------------- dtype probe ----------------
__global__ __launch_bounds__(256) void detect_kernel(
    const void* __restrict__ x, int n, int* __restrict__ modep)
{
    __shared__ float red[256];
    float m = 0.0f;
    for (int i = threadIdx.x; i < n; i += 256) {
        float v = fabsf(bf2f(((const unsigned short*)x)[i]));
        if (!isfinite(v)) v = 1e30f;
        m = fmaxf(m, v);
    }
    red[threadIdx.x] = m;
    __syncthreads();
    for (int s = 128; s; s >>= 1) {
        if (threadIdx.x < s) red[threadIdx.x] = fmaxf(red[threadIdx.x], red[threadIdx.x + s]);
        __syncthreads();
    }
    if (threadIdx.x == 0) *modep = (red[0] > 1e4f) ? 1 : 0;
}

// ---------------- ex MLP ----------------
__global__ __launch_bounds__(256) void ex1_kernel(
    const void* __restrict__ ex, const void* __restrict__ w1,
    const void* __restrict__ b1, float* __restrict__ h1, const int* __restrict__ modep)
{
    const int mode = *modep;
    __shared__ float exs[64];
    const int tid = threadIdx.x;
    const int b = blockIdx.y;
    const int n = blockIdx.x * 256 + tid;
    if (tid < 64) exs[tid] = ldm(ex, b * 64 + tid, mode);
    __syncthreads();
    float acc = ldm(b1, n, mode);
    for (int k = 0; k < 64; k++) acc += exs[k] * ldm(w1, (size_t)k * 2048 + n, mode);
    h1[(size_t)b * 2048 + n] = acc;
}

__global__ __launch_bounds__(256) void ex2_kernel(
    const float* __restrict__ h1, const void* __restrict__ w2,
    const void* __restrict__ b2, float* __restrict__ ex_enc, const int* __restrict__ modep)
{
    const int mode = *modep;
    __shared__ float hs[2048];
    const int tid = threadIdx.x;
    const int b = blockIdx.y;
    const int n = blockIdx.x * 256 + tid;
    for (int idx = tid; idx < 2048; idx += 256) hs[idx] = h1[(size_t)b * 2048 + idx];
    __syncthreads();
    float acc = ldm(b2, n, mode);
    for (int k = 0; k < 2048; k++) acc += hs[k] * ldm(w2, (size_t)k * 512 + n, mode);
    ex_enc[(size_t)b * 512 + n] = tanhf(acc);
}

// ---------------- conv1 ----------------
__global__ __launch_bounds__(256) void conv1_kernel(
    const void* __restrict__ x, const void* __restrict__ w,
    const void* __restrict__ b, f16* __restrict__ out, const int* __restrict__ modep)
{
    const int mode = *modep;
    const int pix = blockIdx.x;
    const int bb = pix / 225, ij = pix % 225;
    const int i = ij / 15, j = ij % 15;
    const int tid = threadIdx.x;
    __shared__ float xs[18];
    if (tid < 18) {
        int c = tid & 1, dj = (tid >> 1) % 3, di = tid / 6;
        int ii = i + di - 1, jj = j + dj - 1;
        float v = 0.0f;
        if (ii >= 0 && ii < 15 && jj >= 0 && jj < 15)
            v = ldm(x, ((size_t)(bb * 15 + ii) * 15 + jj) * 2 + c, mode);
        xs[tid] = v;
    }
    __syncthreads();
    #pragma unroll
    for (int rep = 0; rep < 2; rep++) {
        int n = tid + rep * 256;
        float acc = ldm(b, n, mode);
        #pragma unroll
        for (int t = 0; t < 18; t++) acc += xs[t] * ldm(w, (size_t)t * 512 + n, mode);
        out[(size_t)pix * 512 + n] = (f16)gelu_exact(acc);
    }
}

// ---------------- weight transpose: W[k][n] (ext dtype) -> Wt[n][K] fp16 ----------------
// grid: (N/32, K/32), block 256
__global__ __launch_bounds__(256) void transpose_w(
    const void* __restrict__ W, int ldw, i64 eoff, int K,
    f16* __restrict__ Wt, const int* __restrict__ modep)
{
    const int mode = *modep;
    __shared__ f16 ts[32][33];
    const int k0 = blockIdx.y << 5, n0 = blockIdx.x << 5;
    const int r = threadIdx.x >> 3, c = (threadIdx.x & 7) << 2;
    const size_t base = (size_t)eoff + (size_t)(k0 + r) * ldw + n0 + c;
    #pragma unroll
    for (int q = 0; q < 4; q++) ts[r][c + q] = (f16)ldm(W, base + q, mode);
    __syncthreads();
    f16* dst = Wt + (size_t)(n0 + r) * K + k0 + c;
    #pragma unroll
    for (int q = 0; q < 4; q++) dst[q] = ts[c + q][r];
}

// ---------------- fp16 cast (no transpose), col-window of ext matrix ----------------
// out[r][c] = (f16) W[eoff + r*ldw + c], r<512, c<512; grid 256 blocks x 256
__global__ __launch_bounds__(256) void cast_w(
    const void* __restrict__ W, int ldw, i64 eoff,
    f16* __restrict__ out, const int* __restrict__ modep)
{
    const int mode = *modep;
    const int i0 = (blockIdx.x * 256 + threadIdx.x) << 2;
    const int r = i0 >> 9, c = i0 & 511;
    const size_t base = (size_t)eoff + (size_t)r * ldw + c;
    #pragma unroll
    for (int q = 0; q < 4; q++) out[i0 + q] = (f16)ldm(W, base + q, mode);
}

// ---------------- bcomb = wx_b(v-half) @ wo1 + wo1_b (uses wo1^T fp16) ----------------
__global__ __launch_bounds__(256) void bcomb_kernel(
    const f16* __restrict__ wo1t, const void* __restrict__ wxb, i64 wxb_off,
    const void* __restrict__ wo1b, i64 wo1b_off, float* __restrict__ out,
    const int* __restrict__ modep)
{
    const int mode = *modep;
    const int c = blockIdx.x * 256 + threadIdx.x;
    float acc = ldm(wo1b, (size_t)wo1b_off + c, mode);
    const f16* row = wo1t + (size_t)c * 512;
    for (int d = 0; d < 512; d++)
        acc += ldm(wxb, (size_t)wxb_off + d, mode) * (float)row[d];
    out[c] = acc;
}

// ---------------- MFMA GEMM (fp16 in, fp32 acc, fp16 out) ----------------
// C[row][col] = act( A[a_eoff + z*a_zoff + row*lda + k] @ Wt[z*w_zoff + col*wldw + k]
//                    + bias[b_eoff + z*b_zoff + col] )
// Nvalid: valid output columns per z (stores/bias guarded).
// act: 0 none, 1 gelu, 2 conv2-epilogue. conv: implicit im2col over conv1 output.
// BM=BN=128, BK=32, 4 waves (2x2), wave tile 64x64 (4x4 frags of 16x16x32).
__global__ __launch_bounds__(256) void gemm_mfma(
    const void* __restrict__ A, int lda, int a_ext, i64 a_eoff, i64 a_zoff, int M,
    const f16* __restrict__ Wt, int wldw, i64 w_zoff,
    const void* __restrict__ bias, i64 b_eoff, i64 b_zoff, int b_f32,
    f16* __restrict__ C, int ldc, i64 c_eoff, i64 c_zoff, int Nvalid,
    int K, int act, int conv, const float* __restrict__ ex_enc,
    const int* __restrict__ modep)
{
    const int mode = *modep;
    __shared__ __align__(16) f16 As[128][40];
    __shared__ __align__(16) f16 Bs[128][40];
    const int z = blockIdx.z;
    const i64 a_off = a_eoff + (i64)z * a_zoff;
    const f16* Wz = Wt + (size_t)((i64)z * w_zoff);
    const i64 b_off = b_eoff + (i64)z * b_zoff;
    const i64 c_off = c_eoff + (i64)z * c_zoff;

    const int tid  = threadIdx.x;
    const int lane = tid & 63;
    const int wid  = tid >> 6;
    const int wm   = (wid >> 1) << 6;   // 0 or 64
    const int wn   = (wid & 1) << 6;    // 0 or 64
    const int bm   = blockIdx.y << 7;
    const int bn   = blockIdx.x << 7;

    // staging assignment: thread covers 16 contiguous k of one row
    const int srow = tid >> 1;          // 0..127
    const int scol = (tid & 1) << 4;    // 0 or 16
    const int garow = bm + srow;
    const bool arow_ok = garow < M;

    // conv (implicit im2col) per-thread pixel decomposition
    int cv_base = 0, cv_i = 0, cv_j = 0;
    if (conv) {
        int r = arow_ok ? garow : 0;
        int bb = r / 225, ij = r % 225;
        cv_i = ij / 15; cv_j = ij % 15;
        cv_base = bb * 225;
    }

    f32x4 acc[4][4] = {};

    half8 pa0, pa1, pb0, pb1;
    auto FETCH = [&](int k0) {
        const f16* bp = Wz + (size_t)(bn + srow) * (size_t)wldw + k0 + scol;
        pb0 = *(const half8*)bp;
        pb1 = *(const half8*)(bp + 8);
        pa0 = h8zero(); pa1 = h8zero();
        if (conv) {
            const int t = k0 >> 9;
            const int ii = cv_i + t / 3 - 1, jj = cv_j + t % 3 - 1;
            if (arow_ok && (unsigned)ii < 15u && (unsigned)jj < 15u) {
                const f16* ap = (const f16*)A
                    + ((size_t)(cv_base + ii * 15 + jj) << 9) + (k0 & 511) + scol;
                pa0 = *(const half8*)ap;
                pa1 = *(const half8*)(ap + 8);
            }
        } else if (arow_ok) {
            const size_t aidx = (size_t)a_off + (size_t)garow * lda + k0 + scol;
            if (!a_ext) {
                const f16* ap = (const f16*)A + aidx;
                pa0 = *(const half8*)ap;
                pa1 = *(const half8*)(ap + 8);
            } else if (mode) {
                const float* ap = (const float*)A + aidx;
                float4 f0 = *(const float4*)ap;
                float4 f1 = *(const float4*)(ap + 4);
                float4 f2 = *(const float4*)(ap + 8);
                float4 f3 = *(const float4*)(ap + 12);
                pa0[0]=(f16)f0.x; pa0[1]=(f16)f0.y; pa0[2]=(f16)f0.z; pa0[3]=(f16)f0.w;
                pa0[4]=(f16)f1.x; pa0[5]=(f16)f1.y; pa0[6]=(f16)f1.z; pa0[7]=(f16)f1.w;
                pa1[0]=(f16)f2.x; pa1[1]=(f16)f2.y; pa1[2]=(f16)f2.z; pa1[3]=(f16)f2.w;
                pa1[4]=(f16)f3.x; pa1[5]=(f16)f3.y; pa1[6]=(f16)f3.z; pa1[7]=(f16)f3.w;
            } else {
                const unsigned short* ap = (const unsigned short*)A + aidx;
                pa0 = bf8_cvt(*(const us8*)ap);
                pa1 = bf8_cvt(*(const us8*)(ap + 8));
            }
        }
    };

    FETCH(0);
    const int fra = wm + (lane & 15);
    const int frb = wn + (lane & 15);
    const int fk  = (lane >> 4) << 3;

    for (int k0 = 0; k0 < K; k0 += 32) {
        __syncthreads();   // previous tile's frag reads done
        *(half8*)&As[srow][scol]     = pa0;
        *(half8*)&As[srow][scol + 8] = pa1;
        *(half8*)&Bs[srow][scol]     = pb0;
        *(half8*)&Bs[srow][scol + 8] = pb1;
        __syncthreads();   // tile visible
        if (k0 + 32 < K) FETCH(k0 + 32);   // issue next-tile loads; latency hides under MFMA

        half8 af[4], bv[4];
        #pragma unroll
        for (int m = 0; m < 4; m++) af[m] = *(const half8*)&As[fra + m * 16][fk];
        #pragma unroll
        for (int n = 0; n < 4; n++) bv[n] = *(const half8*)&Bs[frb + n * 16][fk];
        #pragma unroll
        for (int m = 0; m < 4; m++)
            #pragma unroll
            for (int n = 0; n < 4; n++)
                acc[m][n] = __builtin_amdgcn_mfma_f32_16x16x32_f16(af[m], bv[n], acc[m][n], 0, 0, 0);
    }

    // ---------------- epilogue ----------------
    const int ccol0 = bn + wn + (lane & 15);
    float bvv[4];
    #pragma unroll
    for (int n = 0; n < 4; n++) {
        const int col = ccol0 + n * 16;
        float bv = 0.0f;
        if (col < Nvalid && bias)
            bv = b_f32 ? ((const float*)bias)[(size_t)b_off + col]
                       : ldm(bias, (size_t)b_off + col, mode);
        bvv[n] = bv;
    }

    const float LG = 9.210340371976184f / 512.0f;
    const float SQ = 22.627416997969522f;
    float rate[4];
    if (act == 2) {
        #pragma unroll
        for (int n = 0; n < 4; n++) {
            int col = ccol0 + n * 16;
            rate[n] = expf(-(float)(2 * (col >> 1)) * LG);
        }
    }

    #pragma unroll
    for (int m = 0; m < 4; m++) {
        const int rowb = bm + wm + m * 16 + ((lane >> 4) << 2);
        #pragma unroll
        for (int r = 0; r < 4; r++) {
            const int row = rowb + r;
            if (row >= M) continue;
            float pr = 0.0f, pc = 0.0f; int bb = 0;
            if (act == 2) {
                bb = row / 225;
                int ij = row % 225;
                pr = (float)(ij / 15 - 7);
                pc = (float)(ij % 15 - 7);
            }
            #pragma unroll
            for (int n = 0; n < 4; n++) {
                const int col = ccol0 + n * 16;
                if (col >= Nvalid) continue;
                float v = acc[m][n][r] + bvv[n];
                if (act == 1) v = gelu_exact(v);
                else if (act == 2) {
                    float spe = ((col & 1) == 0) ? sinf(pr * rate[n]) : cosf(pc * rate[n]);
                    v = gelu_exact(v) * SQ + ex_enc[(size_t)bb * 512 + col] + spe;
                }
                C[(size_t)c_off + (size_t)row * ldc + col] = (f16)v;
            }
        }
    }
}

// ---------------- fused cross-attention (logits/softmax/pe from enc in LDS) ----------------
// qhpe in: qh[t][512h+e]; out (in-place): pe[t][512h+e] = sum_s softmax_s * enc[t,s,e]
// grid: chunkTok/4 blocks, wave per token; lane = (h,g): h=lane>>3, g=lane&7.
__global__ __launch_bounds__(256) void fused_xattn(
    f16* __restrict__ qhpe, const void* __restrict__ enc,
    const void* __restrict__ mask, int chunk_base, const int* __restrict__ modep)
{
    const int mode = *modep;
    __shared__ f16 encs[4][12][512];
    __shared__ float ms[12];
    const int tid = threadIdx.x;
    const int wid = tid >> 6, lane = tid & 63;

    const size_t row0 = ((size_t)chunk_base + (size_t)blockIdx.x * 4) * 12;
    for (int i4 = tid; i4 < 6144; i4 += 256) {
        const int el = i4 << 2;
        const int tok = el / 6144;
        const int rem = el - tok * 6144;
        const int s = rem >> 9, e = rem & 511;
        const size_t gi = ((row0 + (size_t)tok * 12 + s) << 9) + e;
        float x0, x1, x2, x3;
        if (mode) {
            const float4 v = *(const float4*)((const float*)enc + gi);
            x0 = v.x; x1 = v.y; x2 = v.z; x3 = v.w;
        } else {
            const ushort4 u = *(const ushort4*)((const unsigned short*)enc + gi);
            x0 = bf2f(u.x); x1 = bf2f(u.y); x2 = bf2f(u.z); x3 = bf2f(u.w);
        }
        f16* d = &encs[tok][s][e];
        d[0] = (f16)x0; d[1] = (f16)x1; d[2] = (f16)x2; d[3] = (f16)x3;
    }
    if (tid < 12) ms[tid] = ldm(mask, tid, mode) * (-1e9f);
    __syncthreads();

    const int t_local = blockIdx.x * 4 + wid;
    const int h = lane >> 3, g = lane & 7;
    f16* qrow = qhpe + (size_t)t_local * 4096 + ((size_t)h << 9);

    float l[12];
    #pragma unroll
    for (int s = 0; s < 12; s++) l[s] = 0.0f;
    for (int i = 0; i < 16; i++) {
        const int e = (i << 5) + (g << 2);
        const half4 q4 = *(const half4*)(qrow + e);
        const float q0 = (float)q4[0], q1 = (float)q4[1];
        const float q2v = (float)q4[2], q3 = (float)q4[3];
        #pragma unroll
        for (int s = 0; s < 12; s++) {
            const half4 c4 = *(const half4*)&encs[wid][s][e];
            l[s] += q0 * (float)c4[0] + q1 * (float)c4[1]
                  + q2v * (float)c4[2] + q3 * (float)c4[3];
        }
    }
    #pragma unroll
    for (int m = 1; m <= 4; m <<= 1)
        #pragma unroll
        for (int s = 0; s < 12; s++) l[s] += __shfl_xor(l[s], m);

    float mx = -1e30f;
    #pragma unroll
    for (int s = 0; s < 12; s++) { l[s] = l[s] * 0.125f + ms[s]; mx = fmaxf(mx, l[s]); }
    float p[12], sum = 0.0f;
    #pragma unroll
    for (int s = 0; s < 12; s++) { p[s] = expf(l[s] - mx); sum += p[s]; }
    const float inv = 1.0f / sum;

    for (int i = 0; i < 16; i++) {
        const int e = (i << 5) + (g << 2);
        float a0 = 0, a1 = 0, a2 = 0, a3 = 0;
        #pragma unroll
        for (int s = 0; s < 12; s++) {
            const half4 c4 = *(const half4*)&encs[wid][s][e];
            a0 += p[s] * (float)c4[0]; a1 += p[s] * (float)c4[1];
            a2 += p[s] * (float)c4[2]; a3 += p[s] * (float)c4[3];
        }
        half4 o;
        o[0] = (f16)(a0 * inv); o[1] = (f16)(a1 * inv);
        o[2] = (f16)(a2 * inv); o[3] = (f16)(a3 * inv);
        *(half4*)(qrow + e) = o;
    }
}

// ---------------- layernorm with residual ----------------
__global__ __launch_bounds__(256) void ln_res_kernel(
    const f16* __restrict__ x, const f16* __restrict__ res,
    const void* __restrict__ g, const void* __restrict__ b, i64 gb_eoff,
    void* __restrict__ dst, int dst_ext, const int* __restrict__ modep)
{
    const int mode = *modep;
    const size_t base = (size_t)blockIdx.x * 512;
    const int tid = threadIdx.x;
    float v0 = (float)x[base + tid] + (float)res[base + tid];
    float v1 = (float)x[base + 256 + tid] + (float)res[base + 256 + tid];
    __shared__ float ws[4], ws2[4];
    float s = v0 + v1;
    #pragma unroll
    for (int off = 32; off; off >>= 1) s += __shfl_xor(s, off);
    int wid = tid >> 6, lane = tid & 63;
    if (lane == 0) ws[wid] = s;
    __syncthreads();
    float mean = (ws[0] + ws[1] + ws[2] + ws[3]) * (1.0f / 512.0f);
    float d0 = v0 - mean, d1 = v1 - mean;
    float q = d0 * d0 + d1 * d1;
    #pragma unroll
    for (int off = 32; off; off >>= 1) q += __shfl_xor(q, off);
    if (lane == 0) ws2[wid] = q;
    __syncthreads();
    float var = (ws2[0] + ws2[1] + ws2[2] + ws2[3]) * (1.0f / 512.0f);
    float rs = rsqrtf(var + 1e-6f);
    const size_t go = (size_t)gb_eoff;
    float o0 = d0 * rs * ldm(g, go + tid, mode)       + ldm(b, go + tid, mode);
    float o1 = d1 * rs * ldm(g, go + 256 + tid, mode) + ldm(b, go + 256 + tid, mode);
    if (dst_ext) {
        stm(dst, base + tid,       mode, o0);
        stm(dst, base + 256 + tid, mode, o1);
    } else {
        ((f16*)dst)[base + tid]       = (f16)o0;
        ((f16*)dst)[base + 256 + tid] = (f16)o1;
    }
}

// ---------------- launch ----------------
extern "C" void kernel_launch(void* const* d_in, const int* in_sizes, int n_in,
                              void* d_out, int out_size, void* d_ws, size_t ws_size,
                              hipStream_t stream)
{
    const void* x        = d_in[0];
    const void* ex       = d_in[1];
    const void* enc      = d_in[2];
    const void* pad_mask = d_in[4];
    const void* ex_w1    = d_in[5];
    const void* ex_b1    = d_in[6];
    const void* ex_w2    = d_in[7];
    const void* ex_b2    = d_in[8];
    const void* conv_w1  = d_in[9];
    const void* conv_b1  = d_in[10];
    const void* conv_w2  = d_in[11];
    const void* conv_b2  = d_in[12];
    const void* wx_w     = d_in[13];
    const void* wx_b     = d_in[14];
    const void* wo1_w    = d_in[15];
    const void* wo1_b    = d_in[16];
    const void* wq_w     = d_in[17];
    const void* wq_b     = d_in[18];
    const void* wkv_w    = d_in[19];
    const void* wkv_b    = d_in[20];
    const void* wo2_w    = d_in[21];
    const void* wo2_b    = d_in[22];
    const void* ffn_w1   = d_in[23];
    const void* ffn_b1   = d_in[24];
    const void* ffn_w2   = d_in[25];
    const void* ffn_b2   = d_in[26];
    const void* ln_g     = d_in[27];
    const void* ln_b     = d_in[28];
    (void)in_sizes; (void)n_in; (void)out_size;

    char* wsb = (char*)d_ws;
    size_t off = 0;
    auto alloc = [&](size_t bytes) -> void* {
        void* p = wsb + off; off += (bytes + 255) & ~(size_t)255; return p;
    };
    int*   modep  = (int*)  alloc(256);
    float* ex_h1  = (float*)alloc((size_t)64 * 2048 * 4);
    float* ex_enc = (float*)alloc((size_t)64 * 512 * 4);
    f16*   buf_h  = (f16*)  alloc((size_t)14400 * 512 * 2);
    f16*   buf_a  = (f16*)  alloc((size_t)14400 * 512 * 2);
    f16*   buf_b  = (f16*)  alloc((size_t)14400 * 512 * 2);
    // per-layer weight region (conv2t aliases its start; consumed pre-loop)
    f16*   wt_o1   = (f16*) alloc((size_t)512 * 512 * 2);
    f16*   wt_q    = (f16*) alloc((size_t)512 * 512 * 2);
    f16*   wt_o2   = (f16*) alloc((size_t)512 * 512 * 2);
    f16*   wt_f1   = (f16*) alloc((size_t)2048 * 512 * 2);
    f16*   wt_f2   = (f16*) alloc((size_t)512 * 2048 * 2);
    f16*   wkh     = (f16*) alloc((size_t)512 * 512 * 2);
    f16*   wvT     = (f16*) alloc((size_t)576 * 512 * 2);   // 64 pad rows for BN=128 over-read
    f16*   wxvh    = (f16*) alloc((size_t)512 * 512 * 2);
    f16*   wcombT  = (f16*) alloc((size_t)512 * 512 * 2);
    float* bcomb   = (float*)alloc((size_t)512 * 4);
    f16*   wt_c2   = wt_o1;   // 4608*512 f16 = 4.72 MB <= wt_o1..wt_f2 span (5.77 MB)

    // adaptive tail buffers: FFN intermediate + qh/pe chunk
    const size_t bt_full  = (size_t)14400 * 2048 * 2;   // 59.0 MB
    const size_t bt_chunk = (size_t)4800 * 2048 * 2;    // 19.7 MB
    const size_t qh_full  = (size_t)14400 * 4096 * 2;   // 118.0 MB
    const size_t slack = 1u << 20;
    size_t rem = (ws_size > off) ? ws_size - off : 0;
    int nf, nc;
    if      (rem >= bt_full + qh_full + slack)      { nf = 1; nc = 1; }
    else if (rem >= bt_full + qh_full / 2 + slack)  { nf = 1; nc = 2; }
    else if (rem >= bt_chunk + qh_full / 4 + slack) { nf = 3; nc = 4; }
    else                                            { nf = 3; nc = 8; }
    f16* buf_t = (f16*)alloc(nf == 1 ? bt_full : bt_chunk);
    // nc==8 chunk (14.75 MB) fits in bt_chunk; buf_t is idle during cross-attn
    f16* qhpe = (nc == 8) ? buf_t : (f16*)alloc(qh_full / nc);
    const int chunkTok = 14400 / nc;
    const int nbl = (chunkTok + 127) / 128;

    detect_kernel<<<1, 256, 0, stream>>>(x, 28800, modep);
    ex1_kernel<<<dim3(8, 64), 256, 0, stream>>>(ex, ex_w1, ex_b1, ex_h1, modep);
    ex2_kernel<<<dim3(2, 64), 256, 0, stream>>>(ex_h1, ex_w2, ex_b2, ex_enc, modep);
    conv1_kernel<<<14400, 256, 0, stream>>>(x, conv_w1, conv_b1, buf_t, modep);

    // conv2 as implicit-im2col MFMA GEMM (M=14400, K=4608, N=512)
    transpose_w<<<dim3(16, 144), 256, 0, stream>>>(conv_w2, 512, 0, 4608, wt_c2, modep);
    gemm_mfma<<<dim3(4, 113, 1), 256, 0, stream>>>(
        buf_t, 512, 0, 0, 0, 14400, wt_c2, 4608, 0,
        conv_b2, 0, 0, 0, buf_h, 512, 0, 0, 512, 4608, 2, 1, ex_enc, modep);

    for (int L = 0; L < 4; L++) {
        // weight prep
        transpose_w<<<dim3(16, 16), 256, 0, stream>>>(wo1_w, 512, (i64)L * 512 * 512, 512, wt_o1, modep);
        transpose_w<<<dim3(16, 16), 256, 0, stream>>>(wq_w, 512, (i64)L * 512 * 512, 512, wt_q, modep);
        transpose_w<<<dim3(16, 16), 256, 0, stream>>>(wo2_w, 512, (i64)L * 512 * 512, 512, wt_o2, modep);
        transpose_w<<<dim3(64, 16), 256, 0, stream>>>(ffn_w1, 2048, (i64)L * 512 * 2048, 512, wt_f1, modep);
        transpose_w<<<dim3(16, 64), 256, 0, stream>>>(ffn_w2, 512, (i64)L * 2048 * 512, 2048, wt_f2, modep);
        transpose_w<<<dim3(16, 16), 256, 0, stream>>>(wkv_w, 1024, (i64)L * 512 * 1024 + 512, 512, wvT, modep);
        cast_w<<<256, 256, 0, stream>>>(wkv_w, 1024, (i64)L * 512 * 1024, wkh, modep);
        cast_w<<<256, 256, 0, stream>>>(wx_w, 1536, (i64)L * 512 * 1536 + 1024, wxvh, modep);
        bcomb_kernel<<<2, 256, 0, stream>>>(wt_o1, wx_b, (i64)L * 1536 + 1024,
                                            wo1_b, (i64)L * 512, bcomb, modep);
        // wcombT[c][e] = sum_d wx_v[e,d]*wo1[d,c]  (A = wo1^T, Wt = wxvh)
        gemm_mfma<<<dim3(4, 4, 1), 256, 0, stream>>>(
            wt_o1, 512, 0, 0, 0, 512, wxvh, 512, 0,
            nullptr, 0, 0, 0, wcombT, 512, 0, 0, 512, 512, 0, 0, nullptr, modep);

        // attn1 = h @ wcomb + bcomb   (self-attn T=1 folded through wo1)
        gemm_mfma<<<dim3(4, 113, 1), 256, 0, stream>>>(
            buf_h, 512, 0, 0, 0, 14400, wcombT, 512, 0,
            bcomb, 0, 0, 1, buf_b, 512, 0, 0, 512, 512, 0, 0, nullptr, modep);
        ln_res_kernel<<<14400, 256, 0, stream>>>(
            buf_b, buf_h, ln_g, ln_b, (i64)(L * 3 + 0) * 512, buf_h, 0, modep);

        // q2 = out1 @ wq + b
        gemm_mfma<<<dim3(4, 113, 1), 256, 0, stream>>>(
            buf_h, 512, 0, 0, 0, 14400, wt_q, 512, 0,
            wq_b, (i64)L * 512, 0, 0, buf_a, 512, 0, 0, 512, 512, 0, 0, nullptr, modep);

        // cross attention without materializing K/V:
        // qh = per-head q2 @ wk^T ; fused softmax/pe over enc ; out = per-head pe @ wv + bv
        for (int c = 0; c < nc; c++) {
            const i64 base = (i64)c * chunkTok;
            gemm_mfma<<<dim3(4, nbl, 8), 256, 0, stream>>>(
                buf_a, 512, 0, base * 512, 64, chunkTok, wkh, 512, 64,
                nullptr, 0, 0, 0, qhpe, 4096, 0, 512, 512, 64, 0, 0, nullptr, modep);
            fused_xattn<<<chunkTok / 4, 256, 0, stream>>>(
                qhpe, enc, pad_mask, (int)base, modep);
            gemm_mfma<<<dim3(1, nbl, 8), 256, 0, stream>>>(
                qhpe, 4096, 0, 0, 512, chunkTok, wvT, 512, (i64)64 * 512,
                wkv_b, (i64)L * 1024 + 512, 64, 0,
                buf_b, 512, base * 512, 64, 64, 512, 0, 0, nullptr, modep);
        }

        // attn2 = out @ wo2 + b
        gemm_mfma<<<dim3(4, 113, 1), 256, 0, stream>>>(
            buf_b, 512, 0, 0, 0, 14400, wt_o2, 512, 0,
            wo2_b, (i64)L * 512, 0, 0, buf_a, 512, 0, 0, 512, 512, 0, 0, nullptr, modep);
        ln_res_kernel<<<14400, 256, 0, stream>>>(
            buf_a, buf_h, ln_g, ln_b, (i64)(L * 3 + 1) * 512, buf_h, 0, modep);

        // FFN
        if (nf == 1) {
            gemm_mfma<<<dim3(16, 113, 1), 256, 0, stream>>>(
                buf_h, 512, 0, 0, 0, 14400, wt_f1, 512, 0,
                ffn_b1, (i64)L * 2048, 0, 0, buf_t, 2048, 0, 0, 2048, 512, 1, 0, nullptr, modep);
            gemm_mfma<<<dim3(4, 113, 1), 256, 0, stream>>>(
                buf_t, 2048, 0, 0, 0, 14400, wt_f2, 2048, 0,
                ffn_b2, (i64)L * 512, 0, 0, buf_a, 512, 0, 0, 512, 2048, 0, 0, nullptr, modep);
        } else {
            for (int c = 0; c < 3; c++) {
                gemm_mfma<<<dim3(16, 38, 1), 256, 0, stream>>>(
                    buf_h, 512, 0, (i64)c * 4800 * 512, 0, 4800, wt_f1, 512, 0,
                    ffn_b1, (i64)L * 2048, 0, 0, buf_t, 2048, 0, 0, 2048, 512, 1, 0, nullptr, modep);
                gemm_mfma<<<dim3(4, 38, 1), 256, 0, stream>>>(
                    buf_t, 2048, 0, 0, 0, 4800, wt_f2, 2048, 0,
                    ffn_b2, (i64)L * 512, 0, 0, buf_a, 512, (i64)c * 4800 * 512, 0, 512, 2048, 0, 0, nullptr, modep);
            }
        }
        void* dst = (L == 3) ? d_out : (void*)buf_h;
        ln_res_kernel<<<14400, 256, 0, stream>>>(
            buf_a, buf_h, ln_g, ln_b, (i64)(L * 3 + 2) * 512, dst, (L == 3) ? 1 : 0, modep);
    }
}